// Round 3
// baseline (533.213 us; speedup 1.0000x reference)
//
#include <hip/hip_runtime.h>
#include <hip/hip_bf16.h>

// DFTB Slater-Koster table interpolation.
// Inputs (setup_inputs order):
//   0: rij            [E=2,000,000] float32
//   1: edge_type      [E]           int32
//   2: atom_type      [N=500,000]   int32
//   3: hopping_tables [10,16,512]   float32
//   4: overlap_tables [10,16,512]   float32
//   5: onsiteE        [4,4]         float32
// Outputs (concatenated flat):
//   edge_features [E,16], edge_overlap [E,16], node_features [N,4]
//
// Strategy: transpose tables into ws as [B][512][32] (16 hop + 16 ovl per
// grid point, 128 B contiguous per row) so each edge reads 2 contiguous
// 128 B rows (8x float4) instead of 64 scattered scalar loads.

#define NGRID 512
#define NUM_INGRLS 16
#define N_BOND_TYPES 10
#define ROW_F 32            // floats per transposed row (16 hop + 16 ovl)
#define TRANS_N (N_BOND_TYPES * NUM_INGRLS * NGRID)   // 81920 per table

typedef float v4f __attribute__((ext_vector_type(4)));

__global__ __launch_bounds__(256) void dftb_prep_kernel(
    const float* __restrict__ hop,      // [10][16][512]
    const float* __restrict__ ovl,      // [10][16][512]
    const int*   __restrict__ atype,    // [N]
    const float* __restrict__ onsiteE,  // [4][4]
    float*       __restrict__ ws,       // [10][512][32]
    float*       __restrict__ out_node, // [N][4]
    int N)
{
    int t = blockIdx.x * blockDim.x + threadIdx.x;

    if (t < TRANS_N) {
        // source layout: t = b*8192 + m*512 + i
        int b   = t >> 13;
        int rem = t & 8191;
        int m   = rem >> 9;
        int i   = rem & 511;
        float h = hop[t];
        float o = ovl[t];
        float* dst = ws + ((size_t)(b * NGRID + i)) * ROW_F;
        dst[m]              = h;
        dst[NUM_INGRLS + m] = o;
    }

    if (t < N) {
        int a = atype[t];
        const v4f* src = (const v4f*)onsiteE;
        ((v4f*)out_node)[t] = src[a];
    }
}

__global__ __launch_bounds__(256) void dftb_edge_kernel(
    const float* __restrict__ rij,
    const int*   __restrict__ etype,
    const float* __restrict__ ws,       // [10][512][32] transposed tables
    float* __restrict__ out_hop,
    float* __restrict__ out_ovl,
    int E)
{
    const float X0f = 1.0f;
    const float DXf = (float)((10.0 - 1.0) / (NGRID - 1));

    int e = blockIdx.x * blockDim.x + threadIdx.x;
    if (e >= E) return;

    float r = rij[e];
    int   b = etype[e];

    float t  = (r - X0f) / DXf;
    int   i0 = (int)floorf(t);
    i0 = min(max(i0, 0), NGRID - 2);
    float frac = t - (float)i0;
    float w0   = 1.0f - frac;

    const v4f* row0 = (const v4f*)(ws + ((size_t)(b * NGRID + i0)) * ROW_F);
    const v4f* row1 = row0 + (ROW_F / 4);   // next grid point

    // row layout: [0..3]=hop float4s, [4..7]=ovl float4s
    v4f h0[4], o0[4], h1[4], o1[4];
#pragma unroll
    for (int q = 0; q < 4; ++q) { h0[q] = row0[q];     h1[q] = row1[q];     }
#pragma unroll
    for (int q = 0; q < 4; ++q) { o0[q] = row0[4 + q]; o1[q] = row1[4 + q]; }

    v4f* oh4 = (v4f*)(out_hop + (size_t)e * NUM_INGRLS);
    v4f* oo4 = (v4f*)(out_ovl + (size_t)e * NUM_INGRLS);
#pragma unroll
    for (int q = 0; q < 4; ++q) {
        v4f vh = h0[q] * w0 + h1[q] * frac;
        __builtin_nontemporal_store(vh, &oh4[q]);
        v4f vo = o0[q] * w0 + o1[q] * frac;
        __builtin_nontemporal_store(vo, &oo4[q]);
    }
}

extern "C" void kernel_launch(void* const* d_in, const int* in_sizes, int n_in,
                              void* d_out, int out_size, void* d_ws, size_t ws_size,
                              hipStream_t stream) {
    const float* rij       = (const float*)d_in[0];
    const int*   edge_type = (const int*)  d_in[1];
    const int*   atom_type = (const int*)  d_in[2];
    const float* hop_tab   = (const float*)d_in[3];
    const float* ovl_tab   = (const float*)d_in[4];
    const float* onsiteE   = (const float*)d_in[5];

    const int E = in_sizes[0];
    const int N = in_sizes[2];

    float* out_hop  = (float*)d_out;
    float* out_ovl  = out_hop + (size_t)E * NUM_INGRLS;
    float* out_node = out_ovl + (size_t)E * NUM_INGRLS;

    float* ws = (float*)d_ws;   // needs 10*512*32*4 = 655,360 bytes

    {
        int total = (N > TRANS_N) ? N : TRANS_N;
        dim3 block(256);
        dim3 grid((total + 255) / 256);
        dftb_prep_kernel<<<grid, block, 0, stream>>>(
            hop_tab, ovl_tab, atom_type, onsiteE, ws, out_node, N);
    }
    {
        dim3 block(256);
        dim3 grid((E + 255) / 256);
        dftb_edge_kernel<<<grid, block, 0, stream>>>(
            rij, edge_type, ws, out_hop, out_ovl, E);
    }
}